// Round 1
// baseline (2250.687 us; speedup 1.0000x reference)
//
#include <hip/hip_runtime.h>
#include <math.h>

// Problem constants
#define BB 64
#define SS 2048
#define DD 64
#define EE 64
#define HH 512
#define FF 4
#define NTOK (BB*SS)          // 131072
#define ZELEMS (NTOK*DD)      // 8388608

typedef float f32x4 __attribute__((ext_vector_type(4)));
typedef short s16x8 __attribute__((ext_vector_type(8)));

// bf16 round-to-nearest-even (bits in a short)
__device__ __forceinline__ short f2b(float x) {
  unsigned u = __float_as_uint(x);
  u += 0x7fffu + ((u >> 16) & 1u);
  return (short)(u >> 16);
}

// Abramowitz–Stegun 7.1.26 erf, |err| <= 1.5e-7
__device__ __forceinline__ float erf_approx(float x) {
  float ax = fabsf(x);
  float t = 1.0f / (1.0f + 0.3275911f * ax);
  float p = ((((1.061405429f*t - 1.453152027f)*t + 1.421413741f)*t
              - 0.284496736f)*t + 0.254829592f)*t;
  float r = 1.0f - p * __expf(-ax*ax);
  return (x < 0.0f) ? -r : r;
}
__device__ __forceinline__ float gelu_exact(float x) {
  return 0.5f * x * (1.0f + erf_approx(x * 0.70710678118654752f));
}

// ---------------------------------------------------------------------------
// pack_kernel: fp32 weights -> bf16 MFMA B-fragment layout in workspace.
// Per flow (bf16 elems): W0' (K=96 x 512) 49152 | W1 (512x512) 262144 |
// W2' (512 x cols64..127) 32768.  Fragment: [tile=(kt*NT+nt)][lane][j=0..7],
// value = W[k = kt*32 + (lane>>4)*8 + j][n = nt*16 + (lane&15)].
// Also zeroes ldj (d_out poisoned 0xAA by harness).
// ---------------------------------------------------------------------------
__global__ __launch_bounds__(256) void pack_kernel(
    const float* __restrict__ W0, const float* __restrict__ W1,
    const float* __restrict__ W2, short* __restrict__ wp,
    float* __restrict__ ldj)
{
  int gid = blockIdx.x * 256 + threadIdx.x;
  if (gid < BB) ldj[gid] = 0.f;
  int f = gid / 43008;            // 43008 = 672 tiles * 64 lanes
  if (f >= FF) return;
  int rem = gid - f * 43008;
  int tile = rem >> 6, lane = rem & 63;
  int q = lane >> 4, c = lane & 15;
  short out[8];
  short* dst;
  if (tile < 96) {                       // L0: 3 ktiles x 32 ntiles
    int kt = tile >> 5, nt = tile & 31;
    #pragma unroll
    for (int j = 0; j < 8; j++) {
      int k = kt*32 + q*8 + j;
      int row = (k < 32) ? k : k + 32;   // skip masked-out z rows 32..63
      out[j] = f2b(W0[f*65536 + row*512 + nt*16 + c]);
    }
    dst = wp + f*344064 + (tile*64 + lane)*8;
  } else if (tile < 608) {               // L1: 16 x 32
    int tl = tile - 96;
    int kt = tl >> 5, nt = tl & 31;
    #pragma unroll
    for (int j = 0; j < 8; j++) {
      int k = kt*32 + q*8 + j;
      out[j] = f2b(W1[f*262144 + k*512 + nt*16 + c]);
    }
    dst = wp + f*344064 + 49152 + (tl*64 + lane)*8;
  } else {                               // L2: 16 x 4 (cols 64..127 only)
    int tl = tile - 608;
    int kt = tl >> 2, nt = tl & 3;
    #pragma unroll
    for (int j = 0; j < 8; j++) {
      int k = kt*32 + q*8 + j;
      out[j] = f2b(W2[f*65536 + k*128 + 64 + nt*16 + c]);
    }
    dst = wp + f*344064 + 311296 + (tl*64 + lane)*8;
  }
  *(s16x8*)dst = *(s16x8*)out;
}

// ---------------------------------------------------------------------------
// slogdet: one block (64 threads = 1 wave) per flow; LU w/ partial pivoting
// in LDS; adds S*log|det(conv_W[f])| to every batch's ldj.
// ---------------------------------------------------------------------------
__global__ __launch_bounds__(64) void slogdet_kernel(
    const float* __restrict__ convW, float* __restrict__ ldj)
{
  __shared__ float A[64*65];
  const int f = blockIdx.x;
  const int t = threadIdx.x;
  for (int i = 0; i < 64; i++) A[i*65 + t] = convW[f*4096 + i*64 + t];
  __syncthreads();
  float lad = 0.f;
  for (int k = 0; k < 64; k++) {
    float v = (t >= k) ? fabsf(A[t*65 + k]) : -1.f;
    int p = t;
    #pragma unroll
    for (int off = 32; off; off >>= 1) {
      float ov = __shfl_down(v, off);
      int  op = __shfl_down(p, off);
      if (ov > v) { v = ov; p = op; }
    }
    p = __shfl(p, 0);
    __syncthreads();
    if (p != k) {
      float tmp = A[k*65 + t];
      A[k*65 + t] = A[p*65 + t];
      A[p*65 + t] = tmp;
    }
    __syncthreads();
    float piv = A[k*65 + k];
    lad += logf(fabsf(piv));
    float m = (t > k) ? A[t*65 + k] / piv : 0.f;
    __syncthreads();
    if (t > k) {
      for (int c = k+1; c < 64; c++)
        A[t*65 + c] = fmaf(-m, A[k*65 + c], A[t*65 + c]);
    }
    __syncthreads();
  }
  atomicAdd(&ldj[t], (float)SS * lad);   // same lad on all lanes; t = batch
}

// ---------------------------------------------------------------------------
// an_conv: fused actnorm (+ldj) + z-update + 1x1 conv, fp32.
// 64 tokens/block, 256 threads. Phase1: thread (r=t&63, og=t>>6) computes
// 16 (bias,scale) dot-products with wave-uniform weight addrs (scalar loads).
// Phase2 folded in. Phase3: thread (e=t&63, rg) does conv rows, coalesced out.
// ---------------------------------------------------------------------------
__global__ __launch_bounds__(256) void an_conv_kernel(
    int f, const float* zin, float* zout,
    const int* __restrict__ categ, const float* __restrict__ embed,
    const float* __restrict__ Wa, const float* __restrict__ ba,
    const float* __restrict__ Wc, float* __restrict__ ldj)
{
  __shared__ float ext_s[64*68];
  __shared__ float z_s[64*68];
  const int t = threadIdx.x;
  const int tok0 = blockIdx.x * 64;
  for (int idx = t; idx < 64*64; idx += 256) {
    int r = idx >> 6, e = idx & 63;
    ext_s[r*68 + e] = embed[categ[tok0 + r]*64 + e];
    z_s[r*68 + e]   = zin[(tok0 + r)*64 + e];
  }
  __syncthreads();
  {
    const int r  = t & 63;
    const int og = __builtin_amdgcn_readfirstlane(t >> 6);
    float er[64];
    #pragma unroll
    for (int k = 0; k < 64; k += 4) {
      f32x4 v = *(const f32x4*)&ext_s[r*68 + k];
      er[k] = v[0]; er[k+1] = v[1]; er[k+2] = v[2]; er[k+3] = v[3];
    }
    const float* WaF = Wa + f*8192;
    float lsum = 0.f;
    for (int dd = 0; dd < 16; dd++) {
      int d = og*16 + dd;
      float accB = ba[f*128 + d];
      float accS = ba[f*128 + 64 + d];
      #pragma unroll
      for (int k = 0; k < 64; k++) {
        accB = fmaf(er[k], WaF[k*128 + d],      accB);
        accS = fmaf(er[k], WaF[k*128 + 64 + d], accS);
      }
      float s = tanhf(accS);
      float v = (z_s[r*68 + d] + accB) * __expf(s);
      z_s[r*68 + d] = v;
      lsum += s;
    }
    #pragma unroll
    for (int off = 32; off; off >>= 1) lsum += __shfl_xor(lsum, off);
    if ((t & 63) == 0) atomicAdd(&ldj[tok0 >> 11], lsum);
  }
  __syncthreads();
  {
    const int e  = t & 63;
    const int rg = __builtin_amdgcn_readfirstlane(t >> 6);
    const float* WcF = Wc + f*4096;
    float wc[64];
    #pragma unroll
    for (int k = 0; k < 64; k++) wc[k] = WcF[k*64 + e];   // coalesced per k
    for (int rr = rg*16; rr < rg*16 + 16; rr++) {
      float acc = 0.f;
      #pragma unroll
      for (int k = 0; k < 64; k += 4) {
        f32x4 zv = *(const f32x4*)&z_s[rr*68 + k];        // uniform -> bcast
        acc = fmaf(zv[0], wc[k],   acc);
        acc = fmaf(zv[1], wc[k+1], acc);
        acc = fmaf(zv[2], wc[k+2], acc);
        acc = fmaf(zv[3], wc[k+3], acc);
      }
      zout[(tok0 + rr)*64 + e] = acc;                     // coalesced
    }
  }
}

// ---------------------------------------------------------------------------
// mlp: fused coupling MLP, bf16 MFMA 16x16x32. 128 tokens/block, 8 waves.
// One 128x520 bf16 LDS buffer reused: [z0..31|ext] -> h0 -> h1.
// Waves split the n-dimension: each B fragment loaded exactly once per block.
// L2 (64 out cols) on waves 0..3; epilogue: s/t via shfl_xor, update z ch32..63.
// ---------------------------------------------------------------------------
__global__ __launch_bounds__(512, 2) void mlp_kernel(
    int f, float* z, const int* __restrict__ categ,
    const float* __restrict__ embed, const short* __restrict__ wp,
    const float* __restrict__ b0, const float* __restrict__ b1,
    const float* __restrict__ b2, const float* __restrict__ scal,
    float* __restrict__ ldj)
{
  extern __shared__ short hs[];   // [128][520]
  const int t    = threadIdx.x;
  const int tok0 = blockIdx.x * 128;
  const int lane = t & 63;
  const int w    = __builtin_amdgcn_readfirstlane(t >> 6);
  const int q    = lane >> 4, c16 = lane & 15;
  const short* w0p = wp + f*344064;
  const short* w1p = w0p + 49152;
  const short* w2p = w0p + 311296;
  const f32x4 vzero = {0.f, 0.f, 0.f, 0.f};

  // stage [z ch0..31 | ext] as bf16
  for (int idx = t; idx < 128*32; idx += 512) {
    int r = idx >> 5, c = idx & 31;
    hs[r*520 + c] = f2b(z[(tok0 + r)*64 + c]);
  }
  for (int idx = t; idx < 128*64; idx += 512) {
    int r = idx >> 6, c = idx & 63;
    hs[r*520 + 32 + c] = f2b(embed[categ[tok0 + r]*64 + c]);
  }
  __syncthreads();

  f32x4 acc[8][4];

  // ---- Layer 0: (128 x 96) @ (96 x 512) ----
  #pragma unroll
  for (int rt = 0; rt < 8; rt++)
    #pragma unroll
    for (int nl = 0; nl < 4; nl++) acc[rt][nl] = vzero;
  #pragma unroll
  for (int kt = 0; kt < 3; kt++) {
    s16x8 a[8];
    #pragma unroll
    for (int rt = 0; rt < 8; rt++)
      a[rt] = *(const s16x8*)&hs[(rt*16 + c16)*520 + kt*32 + q*8];
    #pragma unroll
    for (int nl = 0; nl < 4; nl++) {
      int nt = w*4 + nl;
      s16x8 b = *(const s16x8*)&w0p[((kt*32 + nt)*64 + lane)*8];
      #pragma unroll
      for (int rt = 0; rt < 8; rt++)
        acc[rt][nl] = __builtin_amdgcn_mfma_f32_16x16x32_bf16(a[rt], b, acc[rt][nl], 0, 0, 0);
    }
  }
  __syncthreads();   // all waves done reading staged input
  #pragma unroll
  for (int nl = 0; nl < 4; nl++) {
    int nt = w*4 + nl;
    float bias = b0[f*512 + nt*16 + c16];
    #pragma unroll
    for (int rt = 0; rt < 8; rt++)
      #pragma unroll
      for (int i = 0; i < 4; i++)
        hs[(rt*16 + q*4 + i)*520 + nt*16 + c16] = f2b(gelu_exact(acc[rt][nl][i] + bias));
  }
  __syncthreads();

  // ---- Layer 1: (128 x 512) @ (512 x 512) ----
  #pragma unroll
  for (int rt = 0; rt < 8; rt++)
    #pragma unroll
    for (int nl = 0; nl < 4; nl++) acc[rt][nl] = vzero;
  for (int kt = 0; kt < 16; kt++) {
    s16x8 a[8];
    #pragma unroll
    for (int rt = 0; rt < 8; rt++)
      a[rt] = *(const s16x8*)&hs[(rt*16 + c16)*520 + kt*32 + q*8];
    #pragma unroll
    for (int nl = 0; nl < 4; nl++) {
      int nt = w*4 + nl;
      s16x8 b = *(const s16x8*)&w1p[((kt*32 + nt)*64 + lane)*8];
      #pragma unroll
      for (int rt = 0; rt < 8; rt++)
        acc[rt][nl] = __builtin_amdgcn_mfma_f32_16x16x32_bf16(a[rt], b, acc[rt][nl], 0, 0, 0);
    }
  }
  __syncthreads();   // all waves done reading h0
  #pragma unroll
  for (int nl = 0; nl < 4; nl++) {
    int nt = w*4 + nl;
    float bias = b1[f*512 + nt*16 + c16];
    #pragma unroll
    for (int rt = 0; rt < 8; rt++)
      #pragma unroll
      for (int i = 0; i < 4; i++)
        hs[(rt*16 + q*4 + i)*520 + nt*16 + c16] = f2b(gelu_exact(acc[rt][nl][i] + bias));
  }
  __syncthreads();

  // ---- Layer 2: (128 x 512) @ (512 x 64), waves 0..3 only ----
  if (w < 4) {
    f32x4 a2[8];
    #pragma unroll
    for (int rt = 0; rt < 8; rt++) a2[rt] = vzero;
    for (int kt = 0; kt < 16; kt++) {
      s16x8 b = *(const s16x8*)&w2p[((kt*4 + w)*64 + lane)*8];
      #pragma unroll
      for (int rt = 0; rt < 8; rt++) {
        s16x8 a = *(const s16x8*)&hs[(rt*16 + c16)*520 + kt*32 + q*8];
        a2[rt] = __builtin_amdgcn_mfma_f32_16x16x32_bf16(a, b, a2[rt], 0, 0, 0);
      }
    }
    int cc = 64 + w*16 + c16;            // column of original (..,128) nn
    float b2v = b2[f*128 + cc];
    float lsum = 0.f;
    #pragma unroll
    for (int rt = 0; rt < 8; rt++)
      #pragma unroll
      for (int i = 0; i < 4; i++) {
        float val  = a2[rt][i] + b2v;
        float part = __shfl_xor(val, 1); // partner col (s<->t)
        if (!(c16 & 1)) {                // even col: this is s, partner is t
          int d = cc >> 1;               // 32..63
          float sf = __expf(scal[f*64 + d]);
          float mm = fmaxf(sf, 1.0f);
          float s  = tanhf(val / mm) * sf;
          int row = rt*16 + q*4 + i;
          int gi  = (tok0 + row)*64 + d;
          z[gi] = (z[gi] + part) * __expf(s);
          lsum += s;
        }
      }
    #pragma unroll
    for (int off = 32; off; off >>= 1) lsum += __shfl_xor(lsum, off);
    if (lane == 0) atomicAdd(&ldj[tok0 >> 11], lsum);
  }
}

// ---------------------------------------------------------------------------
extern "C" void kernel_launch(void* const* d_in, const int* in_sizes, int n_in,
                              void* d_out, int out_size, void* d_ws, size_t ws_size,
                              hipStream_t stream) {
  (void)in_sizes; (void)n_in; (void)out_size; (void)ws_size;
  const float* z_in  = (const float*)d_in[0];
  const int*   categ = (const int*)  d_in[1];
  const float* embed = (const float*)d_in[2];
  const float* Wa    = (const float*)d_in[3];
  const float* ba    = (const float*)d_in[4];
  const float* Wc    = (const float*)d_in[5];
  const float* scal  = (const float*)d_in[6];
  const float* W0    = (const float*)d_in[7];
  const float* b0    = (const float*)d_in[8];
  const float* W1    = (const float*)d_in[9];
  const float* b1    = (const float*)d_in[10];
  const float* W2    = (const float*)d_in[11];
  const float* b2    = (const float*)d_in[12];

  float* zbuf = (float*)d_out;          // working z lives in d_out
  float* ldj  = zbuf + ZELEMS;
  short* wp   = (short*)d_ws;           // 2.75 MB packed bf16 weights

  hipFuncSetAttribute(reinterpret_cast<const void*>(mlp_kernel),
                      hipFuncAttributeMaxDynamicSharedMemorySize, 133120);

  pack_kernel<<<672, 256, 0, stream>>>(W0, W1, W2, wp, ldj);
  slogdet_kernel<<<4, 64, 0, stream>>>(Wc, ldj);
  for (int f = 0; f < FF; f++) {
    an_conv_kernel<<<NTOK/64, 256, 0, stream>>>(
        f, (f == 0) ? z_in : (const float*)zbuf, zbuf,
        categ, embed, Wa, ba, Wc, ldj);
    mlp_kernel<<<NTOK/128, 512, 133120, stream>>>(
        f, zbuf, categ, embed, wp, b0, b1, b2, scal, ldj);
  }
}

// Round 2
// 1323.211 us; speedup vs baseline: 1.7009x; 1.7009x over previous
//
#include <hip/hip_runtime.h>
#include <math.h>

// Problem constants
#define BB 64
#define SS 2048
#define DD 64
#define EE 64
#define HH 512
#define FF 4
#define NTOK (BB*SS)          // 131072
#define ZELEMS (NTOK*DD)      // 8388608

// packed-weight layout (shorts) in d_ws:
//  [0 .. 1376256)                : MLP W0'/W1/W2' B-frags (4 flows x 344064)
//  [PK2 .. PK2 + 4*24576)        : an_conv Wa/Wc hi+lo B-frags
#define PK2 1376256
#define AN_PER_FLOW 24576         // Wa hi 8192 | Wa lo 8192 | Wc hi 4096 | Wc lo 4096

typedef float f32x4 __attribute__((ext_vector_type(4)));
typedef short s16x8 __attribute__((ext_vector_type(8)));

// bf16 round-to-nearest-even (bits in a short)
__device__ __forceinline__ short f2b(float x) {
  unsigned u = __float_as_uint(x);
  u += 0x7fffu + ((u >> 16) & 1u);
  return (short)(u >> 16);
}
__device__ __forceinline__ float b2f(short h) {
  return __uint_as_float(((unsigned)(unsigned short)h) << 16);
}

// tanh via sigmoid identity: 1 - 2/(exp(2x)+1).  v_exp+v_rcp, ~3e-7 err.
__device__ __forceinline__ float tanh_fast(float x) {
  float e = __expf(2.0f * x);                       // inf for large x is fine
  return 1.0f - 2.0f * __builtin_amdgcn_rcpf(e + 1.0f);
}
// tanh-form GELU: x*sigmoid(1.59577*(x+0.044715x^3)); max |err| ~5e-4
__device__ __forceinline__ float gelu_fast(float x) {
  float u = x * x;
  float p = x * fmaf(0.07135481283f, u, 1.5957691216f);
  float e = __expf(-p);
  return x * __builtin_amdgcn_rcpf(1.0f + e);
}

// ---------------------------------------------------------------------------
// pack_kernel: MLP fp32 weights -> bf16 MFMA B-fragment layout (as round 1).
// Also zeroes ldj.
// ---------------------------------------------------------------------------
__global__ __launch_bounds__(256) void pack_kernel(
    const float* __restrict__ W0, const float* __restrict__ W1,
    const float* __restrict__ W2, short* __restrict__ wp,
    float* __restrict__ ldj)
{
  int gid = blockIdx.x * 256 + threadIdx.x;
  if (gid < BB) ldj[gid] = 0.f;
  int f = gid / 43008;            // 43008 = 672 tiles * 64 lanes
  if (f >= FF) return;
  int rem = gid - f * 43008;
  int tile = rem >> 6, lane = rem & 63;
  int q = lane >> 4, c = lane & 15;
  short out[8];
  short* dst;
  if (tile < 96) {                       // L0: 3 ktiles x 32 ntiles (K=96: z0..31|ext)
    int kt = tile >> 5, nt = tile & 31;
    #pragma unroll
    for (int j = 0; j < 8; j++) {
      int k = kt*32 + q*8 + j;
      int row = (k < 32) ? k : k + 32;   // skip masked-out z rows 32..63
      out[j] = f2b(W0[f*65536 + row*512 + nt*16 + c]);
    }
    dst = wp + f*344064 + (tile*64 + lane)*8;
  } else if (tile < 608) {               // L1: 16 x 32
    int tl = tile - 96;
    int kt = tl >> 5, nt = tl & 31;
    #pragma unroll
    for (int j = 0; j < 8; j++) {
      int k = kt*32 + q*8 + j;
      out[j] = f2b(W1[f*262144 + k*512 + nt*16 + c]);
    }
    dst = wp + f*344064 + 49152 + (tl*64 + lane)*8;
  } else {                               // L2: 16 x 4 (cols 64..127 only)
    int tl = tile - 608;
    int kt = tl >> 2, nt = tl & 3;
    #pragma unroll
    for (int j = 0; j < 8; j++) {
      int k = kt*32 + q*8 + j;
      out[j] = f2b(W2[f*65536 + k*128 + 64 + nt*16 + c]);
    }
    dst = wp + f*344064 + 311296 + (tl*64 + lane)*8;
  }
  *(s16x8*)dst = *(s16x8*)out;
}

// ---------------------------------------------------------------------------
// pack2_kernel: Wa (64x128) and Wc (64x64) -> hi/lo bf16 B-fragments.
// 24 tile-units per flow: u<16 -> Wa tile (kt=u>>3, nt=u&7); u>=16 -> Wc.
// ---------------------------------------------------------------------------
__global__ __launch_bounds__(256) void pack2_kernel(
    const float* __restrict__ Wa, const float* __restrict__ Wc,
    short* __restrict__ wp)
{
  int gid = blockIdx.x * 256 + threadIdx.x;   // 4 * 24 * 64 = 6144 threads
  int f = gid / 1536;
  if (f >= FF) return;
  int rem = gid - f * 1536;
  int u = rem >> 6, lane = rem & 63;
  int q = lane >> 4, c = lane & 15;
  short hi[8], lo[8];
  short* base = wp + PK2 + f*AN_PER_FLOW;
  short* dh; short* dl;
  if (u < 16) {                          // Wa: K=64 (kt 0..1), N=128 (nt 0..7)
    int kt = u >> 3, nt = u & 7;
    #pragma unroll
    for (int j = 0; j < 8; j++) {
      float v = Wa[f*8192 + (kt*32 + q*8 + j)*128 + nt*16 + c];
      hi[j] = f2b(v);
      lo[j] = f2b(v - b2f(hi[j]));
    }
    dh = base + u*512 + lane*8;
    dl = base + 8192 + u*512 + lane*8;
  } else {                               // Wc: K=64, N=64 (nt 0..3)
    int uc = u - 16;
    int kt = uc >> 2, nt = uc & 3;
    #pragma unroll
    for (int j = 0; j < 8; j++) {
      float v = Wc[f*4096 + (kt*32 + q*8 + j)*64 + nt*16 + c];
      hi[j] = f2b(v);
      lo[j] = f2b(v - b2f(hi[j]));
    }
    dh = base + 16384 + uc*512 + lane*8;
    dl = base + 16384 + 4096 + uc*512 + lane*8;
  }
  *(s16x8*)dh = *(s16x8*)hi;
  *(s16x8*)dl = *(s16x8*)lo;
}

// ---------------------------------------------------------------------------
// slogdet: one block (1 wave) per flow; LU w/ partial pivoting in LDS.
// ---------------------------------------------------------------------------
__global__ __launch_bounds__(64) void slogdet_kernel(
    const float* __restrict__ convW, float* __restrict__ ldj)
{
  __shared__ float A[64*65];
  const int f = blockIdx.x;
  const int t = threadIdx.x;
  for (int i = 0; i < 64; i++) A[i*65 + t] = convW[f*4096 + i*64 + t];
  __syncthreads();
  float lad = 0.f;
  for (int k = 0; k < 64; k++) {
    float v = (t >= k) ? fabsf(A[t*65 + k]) : -1.f;
    int p = t;
    #pragma unroll
    for (int off = 32; off; off >>= 1) {
      float ov = __shfl_down(v, off);
      int  op = __shfl_down(p, off);
      if (ov > v) { v = ov; p = op; }
    }
    p = __shfl(p, 0);
    __syncthreads();
    if (p != k) {
      float tmp = A[k*65 + t];
      A[k*65 + t] = A[p*65 + t];
      A[p*65 + t] = tmp;
    }
    __syncthreads();
    float piv = A[k*65 + k];
    lad += logf(fabsf(piv));
    float m = (t > k) ? A[t*65 + k] / piv : 0.f;
    __syncthreads();
    if (t > k) {
      for (int c = k+1; c < 64; c++)
        A[t*65 + c] = fmaf(-m, A[k*65 + c], A[t*65 + c]);
    }
    __syncthreads();
  }
  atomicAdd(&ldj[t], (float)SS * lad);
}

// ---------------------------------------------------------------------------
// an_conv (MFMA, split-bf16): actnorm GEMM (128x128x64) -> z'=(z+b)*exp(tanh s)
// (+ldj) -> conv GEMM (128x64x64) -> z'' global.  D = Ah*Bh + Ah*Bl + Al*Bh
// gives ~2^-16 relative accuracy.  128 tokens/block, 8 waves.
// Wave w: ntb = w&3 (bias cols / conv out cols), scale tile ntb+4; rows
// (w>>2)*64 .. +63 (4 row-tiles).  LDS: ext hi/lo reused for z' hi/lo.
// ---------------------------------------------------------------------------
__global__ __launch_bounds__(512) void an_conv_kernel(
    int f, const float* __restrict__ zin, float* __restrict__ zout,
    const int* __restrict__ categ, const float* __restrict__ embed,
    const float* __restrict__ ba, const short* __restrict__ wp,
    float* __restrict__ ldj)
{
  __shared__ short eh[128*72];
  __shared__ short el[128*72];
  const int t    = threadIdx.x;
  const int tok0 = blockIdx.x * 128;
  const int lane = t & 63;
  const int w    = __builtin_amdgcn_readfirstlane(t >> 6);
  const int q    = lane >> 4, c16 = lane & 15;
  const short* base = wp + PK2 + f*AN_PER_FLOW;
  const f32x4 vzero = {0.f, 0.f, 0.f, 0.f};

  // stage ext = embed[categ] as hi/lo bf16
  for (int idx = t; idx < 128*64; idx += 512) {
    int r = idx >> 6, e = idx & 63;
    float v = embed[categ[tok0 + r]*64 + e];
    short h = f2b(v);
    eh[r*72 + e] = h;
    el[r*72 + e] = f2b(v - b2f(h));
  }
  __syncthreads();

  const int ntb = w & 3;          // bias cols d = ntb*16 + c16
  const int rt0 = (w >> 2) * 4;   // 4 row tiles (64 rows)

  // ---- actnorm GEMM ----
  f32x4 aB[4], aS[4];
  #pragma unroll
  for (int r = 0; r < 4; r++) { aB[r] = vzero; aS[r] = vzero; }
  #pragma unroll
  for (int kt = 0; kt < 2; kt++) {
    s16x8 ah[4], al[4];
    #pragma unroll
    for (int r = 0; r < 4; r++) {
      int row = (rt0 + r)*16 + c16;
      ah[r] = *(const s16x8*)&eh[row*72 + kt*32 + q*8];
      al[r] = *(const s16x8*)&el[row*72 + kt*32 + q*8];
    }
    s16x8 bhB = *(const s16x8*)&base[(kt*8 + ntb)*512 + lane*8];
    s16x8 blB = *(const s16x8*)&base[8192 + (kt*8 + ntb)*512 + lane*8];
    s16x8 bhS = *(const s16x8*)&base[(kt*8 + ntb + 4)*512 + lane*8];
    s16x8 blS = *(const s16x8*)&base[8192 + (kt*8 + ntb + 4)*512 + lane*8];
    #pragma unroll
    for (int r = 0; r < 4; r++) {
      aB[r] = __builtin_amdgcn_mfma_f32_16x16x32_bf16(ah[r], bhB, aB[r], 0,0,0);
      aB[r] = __builtin_amdgcn_mfma_f32_16x16x32_bf16(ah[r], blB, aB[r], 0,0,0);
      aB[r] = __builtin_amdgcn_mfma_f32_16x16x32_bf16(al[r], bhB, aB[r], 0,0,0);
      aS[r] = __builtin_amdgcn_mfma_f32_16x16x32_bf16(ah[r], bhS, aS[r], 0,0,0);
      aS[r] = __builtin_amdgcn_mfma_f32_16x16x32_bf16(ah[r], blS, aS[r], 0,0,0);
      aS[r] = __builtin_amdgcn_mfma_f32_16x16x32_bf16(al[r], bhS, aS[r], 0,0,0);
    }
  }
  __syncthreads();   // done reading ext; eh/el will hold z'

  // ---- epilogue 1: z' = (z + bias) * exp(tanh(scale)); ldj += tanh(scale) ----
  const int d = ntb*16 + c16;
  const float bB = ba[f*128 + d];
  const float bS = ba[f*128 + 64 + d];
  float lsum = 0.f;
  #pragma unroll
  for (int r = 0; r < 4; r++) {
    #pragma unroll
    for (int i = 0; i < 4; i++) {
      int row = (rt0 + r)*16 + q*4 + i;
      float s  = tanh_fast(aS[r][i] + bS);
      float zp = (zin[(tok0 + row)*64 + d] + (aB[r][i] + bB)) * __expf(s);
      lsum += s;
      short h = f2b(zp);
      eh[row*72 + d] = h;
      el[row*72 + d] = f2b(zp - b2f(h));
    }
  }
  #pragma unroll
  for (int off = 32; off; off >>= 1) lsum += __shfl_xor(lsum, off);
  if (lane == 0) atomicAdd(&ldj[tok0 >> 11], lsum);
  __syncthreads();   // z' complete

  // ---- conv GEMM: z'' = z' @ Wc ----
  f32x4 ac[4];
  #pragma unroll
  for (int r = 0; r < 4; r++) ac[r] = vzero;
  #pragma unroll
  for (int kt = 0; kt < 2; kt++) {
    s16x8 ah[4], al[4];
    #pragma unroll
    for (int r = 0; r < 4; r++) {
      int row = (rt0 + r)*16 + c16;
      ah[r] = *(const s16x8*)&eh[row*72 + kt*32 + q*8];
      al[r] = *(const s16x8*)&el[row*72 + kt*32 + q*8];
    }
    s16x8 bh = *(const s16x8*)&base[16384 + (kt*4 + ntb)*512 + lane*8];
    s16x8 bl = *(const s16x8*)&base[16384 + 4096 + (kt*4 + ntb)*512 + lane*8];
    #pragma unroll
    for (int r = 0; r < 4; r++) {
      ac[r] = __builtin_amdgcn_mfma_f32_16x16x32_bf16(ah[r], bh, ac[r], 0,0,0);
      ac[r] = __builtin_amdgcn_mfma_f32_16x16x32_bf16(ah[r], bl, ac[r], 0,0,0);
      ac[r] = __builtin_amdgcn_mfma_f32_16x16x32_bf16(al[r], bh, ac[r], 0,0,0);
    }
  }
  #pragma unroll
  for (int r = 0; r < 4; r++) {
    #pragma unroll
    for (int i = 0; i < 4; i++) {
      int row = (rt0 + r)*16 + q*4 + i;
      zout[(tok0 + row)*64 + d] = ac[r][i];
    }
  }
}

// ---------------------------------------------------------------------------
// mlp: coupling MLP, bf16 MFMA.  64 tokens/block (LDS 66.6 KB -> 2 blocks/CU),
// 8 waves, wave w owns ntiles w*4..w*4+3.  hs reused: input -> h0 -> h1.
// ---------------------------------------------------------------------------
__global__ __launch_bounds__(512, 4) void mlp_kernel(
    int f, float* z, const int* __restrict__ categ,
    const float* __restrict__ embed, const short* __restrict__ wp,
    const float* __restrict__ b0, const float* __restrict__ b1,
    const float* __restrict__ b2, const float* __restrict__ scal,
    float* __restrict__ ldj)
{
  extern __shared__ short hs[];   // [64][520]
  const int t    = threadIdx.x;
  const int tok0 = blockIdx.x * 64;
  const int lane = t & 63;
  const int w    = __builtin_amdgcn_readfirstlane(t >> 6);
  const int q    = lane >> 4, c16 = lane & 15;
  const short* w0p = wp + f*344064;
  const short* w1p = w0p + 49152;
  const short* w2p = w0p + 311296;
  const f32x4 vzero = {0.f, 0.f, 0.f, 0.f};

  // stage [z ch0..31 | ext] as bf16
  for (int idx = t; idx < 64*32; idx += 512) {
    int r = idx >> 5, c = idx & 31;
    hs[r*520 + c] = f2b(z[(tok0 + r)*64 + c]);
  }
  for (int idx = t; idx < 64*64; idx += 512) {
    int r = idx >> 6, c = idx & 63;
    hs[r*520 + 32 + c] = f2b(embed[categ[tok0 + r]*64 + c]);
  }
  __syncthreads();

  f32x4 acc[4][4];

  // ---- Layer 0: (64 x 96) @ (96 x 512) ----
  #pragma unroll
  for (int rt = 0; rt < 4; rt++)
    #pragma unroll
    for (int nl = 0; nl < 4; nl++) acc[rt][nl] = vzero;
  #pragma unroll
  for (int kt = 0; kt < 3; kt++) {
    s16x8 a[4];
    #pragma unroll
    for (int rt = 0; rt < 4; rt++)
      a[rt] = *(const s16x8*)&hs[(rt*16 + c16)*520 + kt*32 + q*8];
    #pragma unroll
    for (int nl = 0; nl < 4; nl++) {
      int nt = w*4 + nl;
      s16x8 b = *(const s16x8*)&w0p[((kt*32 + nt)*64 + lane)*8];
      #pragma unroll
      for (int rt = 0; rt < 4; rt++)
        acc[rt][nl] = __builtin_amdgcn_mfma_f32_16x16x32_bf16(a[rt], b, acc[rt][nl], 0, 0, 0);
    }
  }
  __syncthreads();
  #pragma unroll
  for (int nl = 0; nl < 4; nl++) {
    int nt = w*4 + nl;
    float bias = b0[f*512 + nt*16 + c16];
    #pragma unroll
    for (int rt = 0; rt < 4; rt++)
      #pragma unroll
      for (int i = 0; i < 4; i++)
        hs[(rt*16 + q*4 + i)*520 + nt*16 + c16] = f2b(gelu_fast(acc[rt][nl][i] + bias));
  }
  __syncthreads();

  // ---- Layer 1: (64 x 512) @ (512 x 512) ----
  #pragma unroll
  for (int rt = 0; rt < 4; rt++)
    #pragma unroll
    for (int nl = 0; nl < 4; nl++) acc[rt][nl] = vzero;
  for (int kt = 0; kt < 16; kt++) {
    s16x8 a[4];
    #pragma unroll
    for (int rt = 0; rt < 4; rt++)
      a[rt] = *(const s16x8*)&hs[(rt*16 + c16)*520 + kt*32 + q*8];
    #pragma unroll
    for (int nl = 0; nl < 4; nl++) {
      int nt = w*4 + nl;
      s16x8 b = *(const s16x8*)&w1p[((kt*32 + nt)*64 + lane)*8];
      #pragma unroll
      for (int rt = 0; rt < 4; rt++)
        acc[rt][nl] = __builtin_amdgcn_mfma_f32_16x16x32_bf16(a[rt], b, acc[rt][nl], 0, 0, 0);
    }
  }
  __syncthreads();
  #pragma unroll
  for (int nl = 0; nl < 4; nl++) {
    int nt = w*4 + nl;
    float bias = b1[f*512 + nt*16 + c16];
    #pragma unroll
    for (int rt = 0; rt < 4; rt++)
      #pragma unroll
      for (int i = 0; i < 4; i++)
        hs[(rt*16 + q*4 + i)*520 + nt*16 + c16] = f2b(gelu_fast(acc[rt][nl][i] + bias));
  }
  __syncthreads();

  // ---- Layer 2: (64 x 512) @ (512 x 64), waves 0..3 ----
  if (w < 4) {
    f32x4 a2[4];
    #pragma unroll
    for (int rt = 0; rt < 4; rt++) a2[rt] = vzero;
    for (int kt = 0; kt < 16; kt++) {
      s16x8 b = *(const s16x8*)&w2p[((kt*4 + w)*64 + lane)*8];
      #pragma unroll
      for (int rt = 0; rt < 4; rt++) {
        s16x8 a = *(const s16x8*)&hs[(rt*16 + c16)*520 + kt*32 + q*8];
        a2[rt] = __builtin_amdgcn_mfma_f32_16x16x32_bf16(a, b, a2[rt], 0, 0, 0);
      }
    }
    int cc = 64 + w*16 + c16;            // column of original (..,128) nn
    float b2v = b2[f*128 + cc];
    float lsum = 0.f;
    #pragma unroll
    for (int rt = 0; rt < 4; rt++)
      #pragma unroll
      for (int i = 0; i < 4; i++) {
        float val  = a2[rt][i] + b2v;
        float part = __shfl_xor(val, 1); // partner col (s<->t)
        if (!(c16 & 1)) {                // even col: this is s, partner is t
          int d = cc >> 1;               // 32..63
          float sf = __expf(scal[f*64 + d]);
          float mm = fmaxf(sf, 1.0f);
          float s  = tanh_fast(val / mm) * sf;
          int row = rt*16 + q*4 + i;
          int gi  = (tok0 + row)*64 + d;
          z[gi] = (z[gi] + part) * __expf(s);
          lsum += s;
        }
      }
    #pragma unroll
    for (int off = 32; off; off >>= 1) lsum += __shfl_xor(lsum, off);
    if (lane == 0) atomicAdd(&ldj[tok0 >> 11], lsum);
  }
}

// ---------------------------------------------------------------------------
extern "C" void kernel_launch(void* const* d_in, const int* in_sizes, int n_in,
                              void* d_out, int out_size, void* d_ws, size_t ws_size,
                              hipStream_t stream) {
  (void)in_sizes; (void)n_in; (void)out_size; (void)ws_size;
  const float* z_in  = (const float*)d_in[0];
  const int*   categ = (const int*)  d_in[1];
  const float* embed = (const float*)d_in[2];
  const float* Wa    = (const float*)d_in[3];
  const float* ba    = (const float*)d_in[4];
  const float* Wc    = (const float*)d_in[5];
  const float* scal  = (const float*)d_in[6];
  const float* W0    = (const float*)d_in[7];
  const float* b0    = (const float*)d_in[8];
  const float* W1    = (const float*)d_in[9];
  const float* b1    = (const float*)d_in[10];
  const float* W2    = (const float*)d_in[11];
  const float* b2    = (const float*)d_in[12];

  float* zbuf = (float*)d_out;          // working z lives in d_out
  float* ldj  = zbuf + ZELEMS;
  short* wp   = (short*)d_ws;           // ~2.95 MB packed bf16 weights

  hipFuncSetAttribute(reinterpret_cast<const void*>(mlp_kernel),
                      hipFuncAttributeMaxDynamicSharedMemorySize, 66560);

  pack_kernel<<<672, 256, 0, stream>>>(W0, W1, W2, wp, ldj);
  pack2_kernel<<<24, 256, 0, stream>>>(Wa, Wc, wp);
  slogdet_kernel<<<4, 64, 0, stream>>>(Wc, ldj);
  for (int f = 0; f < FF; f++) {
    an_conv_kernel<<<NTOK/128, 512, 0, stream>>>(
        f, (f == 0) ? z_in : (const float*)zbuf, zbuf,
        categ, embed, ba, wp, ldj);
    mlp_kernel<<<NTOK/64, 512, 66560, stream>>>(
        f, zbuf, categ, embed, wp, b0, b1, b2, scal, ldj);
  }
}